// Round 9
// baseline (248.262 us; speedup 1.0000x reference)
//
#include <hip/hip_runtime.h>
#include <math.h>

// Problem constants
#define B_DIM 8
#define A_DIM 48
#define GF_DIM 256
#define S_DIM 4096
#define P_DIM 32
#define E_DIM 5
#define OHN 100
#define NBINS 65536

typedef __attribute__((ext_vector_type(8))) short short8v;
typedef __attribute__((ext_vector_type(4))) float float4v;

// ---------------- helpers ----------------
__device__ __forceinline__ float wave_sum(float v) {
#pragma unroll
    for (int o = 32; o; o >>= 1) v += __shfl_xor(v, o, 64);
    return v;
}
__device__ __forceinline__ float quad16_sum(float v) {
    v += __shfl_xor(v, 1, 64); v += __shfl_xor(v, 2, 64);
    v += __shfl_xor(v, 4, 64); v += __shfl_xor(v, 8, 64);
    return v;
}
__device__ __forceinline__ unsigned short bf16_rn(float x) {
    unsigned int u = __float_as_uint(x);
    return (unsigned short)((u + 0x7FFFu + ((u >> 16) & 1u)) >> 16);
}
__device__ __forceinline__ float bf16_val(unsigned short h) {
    return __uint_as_float(((unsigned int)h) << 16);
}
__device__ __forceinline__ float4v mfma_bf16(short8v a, short8v b, float4v c) {
    return __builtin_amdgcn_mfma_f32_16x16x32_bf16(a, b, c, 0, 0, 0);
}

// ---------------- prep: W hi/lo streams + vert*mask^2 + mask/ei + zero -------
// Blocks 0..1151: MLP W streams. Blocks 1152..1663: vertB. Block 1664:
// maskB/eiB (grid-stride 384) + zero sums[8]. Blocks 1665..2176: zero spect.
__global__ __launch_bounds__(256) void k_prep(
    const float* __restrict__ cW, const float* __restrict__ l1W,
    const float* __restrict__ l2aW, const float* __restrict__ l2bW,
    const float* __restrict__ vert_feat, const float* __restrict__ vert_mask,
    const float* __restrict__ elem_oh,
    short* __restrict__ wp, short* __restrict__ wv,
    float* __restrict__ maskB, int* __restrict__ eiB,
    float* __restrict__ sums, float4* __restrict__ spect4)
{
    const int blk = blockIdx.x;
    const int tid = threadIdx.x;
    if (blk < 1152) {
        int e = blk * 256 + tid;              // < 36*8192
        int c = e >> 13;
        int i = e & 8191;
        int j    = i & 7;
        int lane = (i >> 3) & 63;
        int nt   = (i >> 9) & 1;
        int wn   = i >> 10;
        int krel = (lane >> 4) * 8 + j;
        int n    = wn * 32 + nt * 16 + (lane & 15);
        float val = 0.f;
        if (c < 12) {
            int kp = c * 32 + krel;
            if (kp < 100)       val = cW[kp * 256 + n];
            else if (kp >= 128) val = cW[(kp - 28) * 256 + n];
        } else {
            int L  = (c - 12) >> 3;
            int kc = (c - 12) & 7;
            const float* W = (L == 0) ? l1W : (L == 1) ? l2aW : l2bW;
            val = W[(kc * 32 + krel) * 256 + n];
        }
        unsigned short h = bf16_rn(val);
        float lo = val - bf16_val(h);
        int base = c * 16384 + (i & 511);
        wp[base + (wn * 4 + nt) * 512]     = (short)h;
        wp[base + (wn * 4 + 2 + nt) * 512] = (short)bf16_rn(lo);
    } else if (blk < 1664) {
        int vb = blk - 1152;
        int vc = vb >> 5;                     // 0..15
        int i  = (vb & 31) * 256 + tid;       // 0..8191
        int b  = vc >> 1, v = vc & 1;
        int j    = i & 7;
        int lane = (i >> 3) & 63;
        int nt   = (i >> 9) & 1;
        int wn   = i >> 10;
        int k = v * 32 + (lane >> 4) * 8 + j;
        int n = wn * 32 + nt * 16 + (lane & 15);
        float val = 0.f;
        if (k < A_DIM) {
            float mk = vert_mask[b * A_DIM + k];
            val = vert_feat[((size_t)(b * A_DIM + k)) * GF_DIM + n] * mk * mk;
        }
        unsigned short h = bf16_rn(val);
        float lo = val - bf16_val(h);
        int base = vc * 16384 + (i & 511);
        wv[base + (wn * 4 + nt) * 512]     = (short)h;
        wv[base + (wn * 4 + 2 + nt) * 512] = (short)bf16_rn(lo);
    } else if (blk == 1664) {
        for (int t = tid; t < B_DIM * A_DIM; t += 256) {
            maskB[t] = vert_mask[t];
            int ei = 0;
#pragma unroll
            for (int e = 0; e < E_DIM; ++e)
                if (elem_oh[t * E_DIM + e] > 0.5f) ei = e;
            eiB[t] = ei;
        }
        if (tid < B_DIM) sums[tid] = 0.0f;
    } else {
        int z = (blk - 1665) * 256 + tid;     // 512 blocks x 256 x float4
        spect4[z] = make_float4(0.f, 0.f, 0.f, 0.f);
    }
}

// ---------------- MLP kernel: M=32/block, 3 blocks/CU (LDS-limited) ---------
// LDS: xAh 24576 | xAl 16384 | fm 4096 | ps 1024 | cnt 640 | invsz 128
#define L_XAL 24576
#define L_FM  40960
#define L_PS  45056
#define L_CNT 46080
#define L_INV 46720
#define L_TOT 46848

// One GEMM layer, barrier-free K loop; W in regs, depth-1 double buffer
// (2-slot ring = 32 VGPRs for W — fits the ~64-VGPR budget; the R8 3-slot
// ring needed 48 and was demoted by the allocator).
template <int NKC, int LO0, int ACT, bool NORM, bool SCORE>
__device__ __forceinline__ void layer_pass(
    short* xAh, short* xAl, float (*ps)[32],
    const short* __restrict__ wstream, const float* __restrict__ bias,
    const float* __restrict__ sW, const float* __restrict__ sb,
    float* __restrict__ scores, float* __restrict__ sums, int R0)
{
    const int tid  = threadIdx.x;
    const int lane = tid & 63;
    const int wn   = tid >> 6;
    const int quad = lane >> 4;
    const int col  = lane & 15;
    const short* wbase = wstream + wn * 2048 + lane * 8;

    float4v acc[2][2];
#pragma unroll
    for (int mi = 0; mi < 2; ++mi)
#pragma unroll
        for (int nt = 0; nt < 2; ++nt) acc[mi][nt] = (float4v){0.f, 0.f, 0.f, 0.f};

    short8v bh[2][2], bl[2][2];
    bh[0][0] = *(const short8v*)(wbase);
    bh[0][1] = *(const short8v*)(wbase + 512);
    bl[0][0] = *(const short8v*)(wbase + 1024);
    bl[0][1] = *(const short8v*)(wbase + 1536);

#pragma unroll
    for (int kc = 0; kc < NKC; ++kc) {
        const int cur = kc & 1;
        if (kc + 1 < NKC) {
            const short* q = wbase + (kc + 1) * 16384;
            bh[cur ^ 1][0] = *(const short8v*)(q);
            bh[cur ^ 1][1] = *(const short8v*)(q + 512);
            bl[cur ^ 1][0] = *(const short8v*)(q + 1024);
            bl[cur ^ 1][1] = *(const short8v*)(q + 1536);
        }
        short8v ah[2], al[2];
#pragma unroll
        for (int mi = 0; mi < 2; ++mi)
            ah[mi] = *(const short8v*)(xAh + ((kc * 2 + mi) * 64 + lane) * 8);
        const bool hlo = (kc >= LO0);
        if (hlo) {
#pragma unroll
            for (int mi = 0; mi < 2; ++mi)
                al[mi] = *(const short8v*)(xAl + (((kc - LO0) * 2 + mi) * 64 + lane) * 8);
        }
#pragma unroll
        for (int mi = 0; mi < 2; ++mi)
#pragma unroll
            for (int nt = 0; nt < 2; ++nt) {
                acc[mi][nt] = mfma_bf16(ah[mi], bh[cur][nt], acc[mi][nt]);
                acc[mi][nt] = mfma_bf16(ah[mi], bl[cur][nt], acc[mi][nt]);
                if (hlo)
                    acc[mi][nt] = mfma_bf16(al[mi], bh[cur][nt], acc[mi][nt]);
            }
    }

    // bias + activation
    float bc0 = bias[wn * 32 + col];
    float bc1 = bias[wn * 32 + 16 + col];
#pragma unroll
    for (int mi = 0; mi < 2; ++mi)
#pragma unroll
        for (int r = 0; r < 4; ++r) {
            float z0 = acc[mi][0][r] + bc0;
            float z1 = acc[mi][1][r] + bc1;
            if (ACT == 0) { z0 = fmaxf(z0, 0.f); z1 = fmaxf(z1, 0.f); }
            else { z0 = (z0 > 0.f) ? z0 : 0.01f * z0; z1 = (z1 > 0.f) ? z1 : 0.01f * z1; }
            acc[mi][0][r] = z0; acc[mi][1][r] = z1;
        }

    __syncthreads();   // all xA reads of this layer done

    if (NORM) {
        float rsum[2][4];
#pragma unroll
        for (int mi = 0; mi < 2; ++mi)
#pragma unroll
            for (int r = 0; r < 4; ++r)
                rsum[mi][r] = quad16_sum(acc[mi][0][r] + acc[mi][1][r]);
        if (col == 0) {
#pragma unroll
            for (int mi = 0; mi < 2; ++mi)
#pragma unroll
                for (int r = 0; r < 4; ++r)
                    ps[wn][mi * 16 + quad * 4 + r] = rsum[mi][r];
        }
        __syncthreads();
        float mu[2][4];
#pragma unroll
        for (int mi = 0; mi < 2; ++mi)
#pragma unroll
            for (int r = 0; r < 4; ++r) {
                int m = mi * 16 + quad * 4 + r;
                float s = 0.f;
#pragma unroll
                for (int w = 0; w < 8; ++w) s += ps[w][m];
                mu[mi][r] = s * (1.f / 256.f);
            }
        __syncthreads();
        float qs[2][4];
#pragma unroll
        for (int mi = 0; mi < 2; ++mi)
#pragma unroll
            for (int r = 0; r < 4; ++r) {
                acc[mi][0][r] -= mu[mi][r];
                acc[mi][1][r] -= mu[mi][r];
                float q = acc[mi][0][r] * acc[mi][0][r]
                        + acc[mi][1][r] * acc[mi][1][r];
                qs[mi][r] = quad16_sum(q);
            }
        if (col == 0) {
#pragma unroll
            for (int mi = 0; mi < 2; ++mi)
#pragma unroll
                for (int r = 0; r < 4; ++r)
                    ps[wn][mi * 16 + quad * 4 + r] = qs[mi][r];
        }
        __syncthreads();
#pragma unroll
        for (int mi = 0; mi < 2; ++mi)
#pragma unroll
            for (int r = 0; r < 4; ++r) {
                int m = mi * 16 + quad * 4 + r;
                float s = 0.f;
#pragma unroll
                for (int w = 0; w < 8; ++w) s += ps[w][m];
                float rsf = 1.0f / sqrtf(s * (1.f / 256.f) + 1e-5f);
                acc[mi][0][r] *= rsf;
                acc[mi][1][r] *= rsf;
            }
    }

    if (SCORE) {
        __syncthreads();
        float sv0 = sW[wn * 32 + col];
        float sv1 = sW[wn * 32 + 16 + col];
        float psu[2][4];
#pragma unroll
        for (int mi = 0; mi < 2; ++mi)
#pragma unroll
            for (int r = 0; r < 4; ++r)
                psu[mi][r] = quad16_sum(acc[mi][0][r] * sv0 + acc[mi][1][r] * sv1);
        if (col == 0) {
#pragma unroll
            for (int mi = 0; mi < 2; ++mi)
#pragma unroll
                for (int r = 0; r < 4; ++r)
                    ps[wn][mi * 16 + quad * 4 + r] = psu[mi][r];
        }
        __syncthreads();
        if (tid < 32) {
            float s = sb[0];
#pragma unroll
            for (int w = 0; w < 8; ++w) s += ps[w][tid];
            scores[R0 + tid] = s;
            // per-batch sum of exp(score): |score| <= ~16 (Cauchy-Schwarz on
            // inorm output), so no max-subtraction needed; exp(16)=8.9e6 safe.
            float e = expf(s);
            e += __shfl_xor(e, 16, 64); e += __shfl_xor(e, 8, 64);
            e += __shfl_xor(e, 4, 64);  e += __shfl_xor(e, 2, 64);
            e += __shfl_xor(e, 1, 64);
            if (tid == 0) atomicAdd(&sums[R0 >> 12], e);
        }
    } else {
        // writeback to next layer's A-frag layout; wave wn owns k-chunk wn.
#pragma unroll
        for (int mi = 0; mi < 2; ++mi)
#pragma unroll
            for (int nt = 0; nt < 2; ++nt) {
                int nn0 = (nt * 16 + col) & ~1;
                int q2  = nn0 >> 3;
                int j0  = nn0 & 7;
#pragma unroll
                for (int r = 0; r < 4; ++r) {
                    float v  = acc[mi][nt][r];
                    float pv = __shfl_xor(v, 1, 64);
                    int m15 = quad * 4 + r;
                    int rowidx = (wn * 2 + mi) * 64 + q2 * 16 + m15;
                    if ((col & 1) == 0) {
                        unsigned int wd = (unsigned int)bf16_rn(v)
                                        | ((unsigned int)bf16_rn(pv) << 16);
                        ((unsigned int*)xAh)[rowidx * 4 + (j0 >> 1)] = wd;
                    } else {
                        float ls = v  - bf16_val(bf16_rn(v));
                        float lp = pv - bf16_val(bf16_rn(pv));
                        unsigned int wd = (unsigned int)bf16_rn(lp)
                                        | ((unsigned int)bf16_rn(ls) << 16);
                        ((unsigned int*)xAl)[rowidx * 4 + (j0 >> 1)] = wd;
                    }
                }
            }
        __syncthreads();
    }
}

// launch_bounds (512,4): (512,6) spilled 57 MB (R7); 52 VGPR at (512,4) is
// spill-free and LDS (46.8 KB) keeps 3 blocks/CU.
__global__ __launch_bounds__(512, 4) void k_mlp(
    const int* __restrict__ subsets, const short* __restrict__ wprep,
    const short* __restrict__ vertB,
    const float* __restrict__ maskB, const int* __restrict__ eiB,
    const float* __restrict__ cb,  const float* __restrict__ l1b,
    const float* __restrict__ l2ab, const float* __restrict__ l2bb,
    const float* __restrict__ sW,  const float* __restrict__ sb,
    float* __restrict__ scores, float* __restrict__ sums)
{
    __shared__ __align__(16) char smem[L_TOT];
    short*  xAh = (short*)smem;
    short*  xAl = (short*)(smem + L_XAL);
    short*  fm  = (short*)(smem + L_FM);
    float (*ps)[32]  = (float(*)[32])(smem + L_PS);
    float (*cnt)[5]  = (float(*)[5])(smem + L_CNT);
    float*  invsz    = (float*)(smem + L_INV);

    const int tid  = threadIdx.x;
    const int lane = tid & 63;
    const int wn   = tid >> 6;
    const int quad = lane >> 4;
    const int col  = lane & 15;
    const int fb   = blockIdx.x;          // 0..1023, 32 rows each
    const int b    = fb >> 7;
    const int R0   = fb * 32;

    // ---- phase A1: subset flags -> exact-bf16 A-frags (K=64, k>=48 zero) ----
    if (tid < 256) {
        int g  = tid;
        int lg = g & 63;
        int t2 = g >> 6;                  // kc*2 + mi
        int kc = t2 >> 1, mi = t2 & 1;
        int m  = mi * 16 + (lg & 15);
        int k0 = kc * 32 + (lg >> 4) * 8;
        const int* srow = subsets + (size_t)(R0 + m) * A_DIM;
        short8v hv;
#pragma unroll
        for (int j = 0; j < 8; ++j) {
            int k = k0 + j;
            hv[j] = (short)((k < A_DIM && srow[k]) ? 0x3F80 : 0);
        }
        *(short8v*)(fm + g * 8) = hv;
    }

    // ---- phase A2: per-row element counts (ballot) + 1/subset_size ----
    {
        const float mymask = (lane < A_DIM) ? maskB[b * A_DIM + lane] : 0.f;
        const int   myei   = (lane < A_DIM) ? eiB[b * A_DIM + lane]   : -1;
#pragma unroll
        for (int i = 0; i < 4; ++i) {
            int r = wn * 4 + i;
            int fl = (lane < A_DIM) ? subsets[(size_t)(R0 + r) * A_DIM + lane] : 0;
            unsigned long long m0 = __ballot(fl != 0 && myei == 0);
            unsigned long long m1 = __ballot(fl != 0 && myei == 1);
            unsigned long long m2 = __ballot(fl != 0 && myei == 2);
            unsigned long long m3 = __ballot(fl != 0 && myei == 3);
            unsigned long long m4 = __ballot(fl != 0 && myei == 4);
            float ssz = wave_sum(fl ? mymask : 0.f) + 1e-4f;
            if (lane == 0) {
                cnt[r][0] = (float)__popcll(m0);
                cnt[r][1] = (float)__popcll(m1);
                cnt[r][2] = (float)__popcll(m2);
                cnt[r][3] = (float)__popcll(m3);
                cnt[r][4] = (float)__popcll(m4);
                invsz[r]  = 1.0f / ssz;
            }
        }
    }
    __syncthreads();

    // ---- layer 0: sws = flags @ (vert*mask^2), /size, inorm -> combine input
    {
        const short* wbase = vertB + b * 32768 + wn * 2048 + lane * 8;
        float4v acc[2][2];
#pragma unroll
        for (int mi = 0; mi < 2; ++mi)
#pragma unroll
            for (int nt = 0; nt < 2; ++nt) acc[mi][nt] = (float4v){0.f, 0.f, 0.f, 0.f};

        short8v bh[2][2], bl[2][2];
#pragma unroll
        for (int kc = 0; kc < 2; ++kc) {
            const short* q = wbase + kc * 16384;
            bh[kc][0] = *(const short8v*)(q);
            bh[kc][1] = *(const short8v*)(q + 512);
            bl[kc][0] = *(const short8v*)(q + 1024);
            bl[kc][1] = *(const short8v*)(q + 1536);
        }
#pragma unroll
        for (int kc = 0; kc < 2; ++kc) {
            short8v a0 = *(const short8v*)(fm + ((kc * 2 + 0) * 64 + lane) * 8);
            short8v a1 = *(const short8v*)(fm + ((kc * 2 + 1) * 64 + lane) * 8);
#pragma unroll
            for (int nt = 0; nt < 2; ++nt) {
                acc[0][nt] = mfma_bf16(a0, bh[kc][nt], acc[0][nt]);
                acc[0][nt] = mfma_bf16(a0, bl[kc][nt], acc[0][nt]);
                acc[1][nt] = mfma_bf16(a1, bh[kc][nt], acc[1][nt]);
                acc[1][nt] = mfma_bf16(a1, bl[kc][nt], acc[1][nt]);
            }
        }

        // mean = sws / subset_size
#pragma unroll
        for (int mi = 0; mi < 2; ++mi)
#pragma unroll
            for (int r = 0; r < 4; ++r) {
                float iv = invsz[mi * 16 + quad * 4 + r];
                acc[mi][0][r] *= iv;
                acc[mi][1][r] *= iv;
            }

        __syncthreads();

        // instance norm over 256 cols
        {
            float rsum[2][4];
#pragma unroll
            for (int mi = 0; mi < 2; ++mi)
#pragma unroll
                for (int r = 0; r < 4; ++r)
                    rsum[mi][r] = quad16_sum(acc[mi][0][r] + acc[mi][1][r]);
            if (col == 0) {
#pragma unroll
                for (int mi = 0; mi < 2; ++mi)
#pragma unroll
                    for (int r = 0; r < 4; ++r)
                        ps[wn][mi * 16 + quad * 4 + r] = rsum[mi][r];
            }
            __syncthreads();
            float mu[2][4];
#pragma unroll
            for (int mi = 0; mi < 2; ++mi)
#pragma unroll
                for (int r = 0; r < 4; ++r) {
                    int m = mi * 16 + quad * 4 + r;
                    float s = 0.f;
#pragma unroll
                    for (int w = 0; w < 8; ++w) s += ps[w][m];
                    mu[mi][r] = s * (1.f / 256.f);
                }
            __syncthreads();
            float qs[2][4];
#pragma unroll
            for (int mi = 0; mi < 2; ++mi)
#pragma unroll
                for (int r = 0; r < 4; ++r) {
                    acc[mi][0][r] -= mu[mi][r];
                    acc[mi][1][r] -= mu[mi][r];
                    float q = acc[mi][0][r] * acc[mi][0][r]
                            + acc[mi][1][r] * acc[mi][1][r];
                    qs[mi][r] = quad16_sum(q);
                }
            if (col == 0) {
#pragma unroll
                for (int mi = 0; mi < 2; ++mi)
#pragma unroll
                    for (int r = 0; r < 4; ++r)
                        ps[wn][mi * 16 + quad * 4 + r] = qs[mi][r];
            }
            __syncthreads();
#pragma unroll
            for (int mi = 0; mi < 2; ++mi)
#pragma unroll
                for (int r = 0; r < 4; ++r) {
                    int m = mi * 16 + quad * 4 + r;
                    float s = 0.f;
#pragma unroll
                    for (int w = 0; w < 8; ++w) s += ps[w][m];
                    float rsf = 1.0f / sqrtf(s * (1.f / 256.f) + 1e-5f);
                    acc[mi][0][r] *= rsf;
                    acc[mi][1][r] *= rsf;
                }
        }

        // writeback: normed cols n -> combine k' = 128+n (xAh kc 4+wn, xAl chunk wn)
#pragma unroll
        for (int mi = 0; mi < 2; ++mi)
#pragma unroll
            for (int nt = 0; nt < 2; ++nt) {
                int nn0 = (nt * 16 + col) & ~1;
                int q2  = nn0 >> 3;
                int j0  = nn0 & 7;
#pragma unroll
                for (int r = 0; r < 4; ++r) {
                    float v  = acc[mi][nt][r];
                    float pv = __shfl_xor(v, 1, 64);
                    int m15 = quad * 4 + r;
                    int rh = ((4 + wn) * 2 + mi) * 64 + q2 * 16 + m15;
                    int rl = (wn * 2 + mi) * 64 + q2 * 16 + m15;
                    if ((col & 1) == 0) {
                        unsigned int wd = (unsigned int)bf16_rn(v)
                                        | ((unsigned int)bf16_rn(pv) << 16);
                        ((unsigned int*)xAh)[rh * 4 + (j0 >> 1)] = wd;
                    } else {
                        float ls = v  - bf16_val(bf16_rn(v));
                        float lp = pv - bf16_val(bf16_rn(pv));
                        unsigned int wd = (unsigned int)bf16_rn(lp)
                                        | ((unsigned int)bf16_rn(ls) << 16);
                        ((unsigned int*)xAl)[rl * 4 + (j0 >> 1)] = wd;
                    }
                }
            }

        // thermometer frags into xAh kc 0..3 (512 groups == 512 threads)
        {
            int g  = tid;
            int lg = g & 63;
            int t2 = g >> 6;                 // kc*2 + mi, kc 0..3
            int kc = t2 >> 1, mi = t2 & 1;
            int m  = mi * 16 + (lg & 15);
            int kb = (lg >> 4) * 8;
            float c0 = cnt[m][0], c1 = cnt[m][1], c2 = cnt[m][2],
                  c3 = cnt[m][3], c4 = cnt[m][4];
            short8v hv;
#pragma unroll
            for (int j = 0; j < 8; ++j) {
                int kp = kc * 32 + kb + j;
                float val = 0.f;
                if (kp < 100) {
                    int e = kp / 20;
                    float ce = (e == 0) ? c0 : (e == 1) ? c1 : (e == 2) ? c2
                             : (e == 3) ? c3 : c4;
                    val = ((float)(kp - e * 20) < ce) ? 1.0f : 0.0f;
                }
                hv[j] = (short)((val != 0.f) ? 0x3F80 : 0);
            }
            *(short8v*)(xAh + g * 8) = hv;
        }
        __syncthreads();
    }

    // ---- layers 1..4 ----
    layer_pass<12, 4, 0, true,  false>(xAh, xAl, ps, wprep,
        cb, nullptr, nullptr, nullptr, nullptr, R0);
    layer_pass< 8, 0, 0, false, false>(xAh, xAl, ps, wprep + 12 * 16384,
        l1b, nullptr, nullptr, nullptr, nullptr, R0);
    layer_pass< 8, 0, 1, false, false>(xAh, xAl, ps, wprep + 20 * 16384,
        l2ab, nullptr, nullptr, nullptr, nullptr, R0);
    layer_pass< 8, 0, 0, true,  true >(xAh, xAl, ps, wprep + 28 * 16384,
        l2bb, sW, sb, scores, sums, R0);
}

// ---------------- scatter (computes probs inline; softmax kernel removed) ----
__global__ __launch_bounds__(256) void k_scatter(
    const int*   __restrict__ mass_idx,
    const float* __restrict__ intensity,
    const float* __restrict__ scores,    // raw scores (ws)
    const float* __restrict__ sums,      // per-batch sum(exp(s))
    float* __restrict__ probs,           // output probs (B*S)
    float* __restrict__ spect)
{
    int i  = blockIdx.x * 256 + threadIdx.x;   // < 1048576
    int bs = i >> 5;
    int b  = i >> 17;
    float p = expf(scores[bs]) * (1.0f / sums[b]);
    if ((i & 31) == 0) probs[bs] = p;
    float w = intensity[i] * p;
    unsafeAtomicAdd(spect + ((size_t)b << 16) + mass_idx[i], w);
}

// ---------------- launch ----------------
extern "C" void kernel_launch(void* const* d_in, const int* in_sizes, int n_in,
                              void* d_out, int out_size, void* d_ws, size_t ws_size,
                              hipStream_t stream) {
    const float* vert_feat = (const float*)d_in[0];
    const float* vert_mask = (const float*)d_in[1];
    const float* elem_oh   = (const float*)d_in[2];
    const int*   subsets   = (const int*)d_in[4];
    const int*   mass_idx  = (const int*)d_in[6];
    const float* intensity = (const float*)d_in[7];
    const float* combine_W = (const float*)d_in[8];
    const float* combine_b = (const float*)d_in[9];
    const float* l1_W      = (const float*)d_in[10];
    const float* l1_b      = (const float*)d_in[11];
    const float* l2a_W     = (const float*)d_in[12];
    const float* l2a_b     = (const float*)d_in[13];
    const float* l2b_W     = (const float*)d_in[14];
    const float* l2b_b     = (const float*)d_in[15];
    const float* score_W   = (const float*)d_in[16];
    const float* score_b   = (const float*)d_in[17];

    float* out   = (float*)d_out;
    float* spect = out;                           // B*NBINS
    float* probs = out + (size_t)B_DIM * NBINS;   // B*S

    short* wprep  = (short*)d_ws;                 // 36*16384 shorts
    short* vertB  = wprep + 36 * 16384;           // 16*16384 shorts
    float* maskB  = (float*)(vertB + 16 * 16384); // 384 f32
    int*   eiB    = (int*)(maskB + B_DIM * A_DIM);// 384 int
    float* sums   = (float*)(eiB + B_DIM * A_DIM);// 8 f32
    float* scores = sums + 8;                     // 32768 f32 (raw scores)

    k_prep<<<2177, 256, 0, stream>>>(combine_W, l1_W, l2a_W, l2b_W,
        vert_feat, vert_mask, elem_oh, wprep, vertB, maskB, eiB, sums,
        (float4*)spect);
    k_mlp<<<1024, 512, 0, stream>>>(subsets, wprep, vertB, maskB, eiB,
        combine_b, l1_b, l2a_b, l2b_b, score_W, score_b, scores, sums);
    k_scatter<<<(B_DIM * S_DIM * P_DIM) / 256, 256, 0, stream>>>(
        mass_idx, intensity, scores, sums, probs, spect);
}